// Round 12
// baseline (320.308 us; speedup 1.0000x reference)
//
#include <hip/hip_runtime.h>
#include <stdint.h>

#define NROWS (512*256)          // 131072
#define DDIM 128
#define KCB 1024
#define TOTALF (NROWS*DDIM)      // 16777216
#define TAU 0.35f                // refine gate vs 2nd-best gap (r5-proven)
#define IDXMASK 0xFFFFFC00u      // clear low 10 mantissa bits for packed argmin keys

typedef __attribute__((ext_vector_type(8))) short short8v;
typedef __attribute__((ext_vector_type(4))) float f32x4;
typedef __attribute__((ext_vector_type(16))) float f32x16;

static __device__ __forceinline__ unsigned short bf16_rne(float f) {
    unsigned u = __builtin_bit_cast(unsigned, f);
    u += 0x7FFFu + ((u >> 16) & 1u);
    return (unsigned short)(u >> 16);
}
static __device__ __forceinline__ float bf16_to_f32(unsigned short h) {
    unsigned u = ((unsigned)h) << 16;
    return __builtin_bit_cast(float, u);
}

// ---- prep (r11-proven): 32 blocks; block ct handles cols [ct*32, ct*32+32).
// Blob: [ct 0..31][ks 0..7][1024B]; seg ks lane l: col=ct*32+(l&31), d=ks*16+(l>>5)*8+j
__global__ __launch_bounds__(256) void vq_prep(
    const float* __restrict__ emb,
    float* __restrict__ ebT_f32,
    char* __restrict__ ebfrag,
    float* __restrict__ enorm)
{
    __shared__ float T[128 * 33];
    __shared__ float red[256];
    const int t = threadIdx.x;
    const int ct = blockIdx.x;
    const int k0 = ct * 32;
    {
        const int c = t & 31;
        const int dq = t >> 5;
        #pragma unroll
        for (int i = 0; i < 16; ++i) {
            int d = dq * 16 + i;
            T[d * 33 + c] = emb[(size_t)d * KCB + k0 + c];
        }
    }
    __syncthreads();
    {
        const int c = t & 31, part = t >> 5;
        float s = 0.f;
        #pragma unroll
        for (int i = 0; i < 16; ++i) { float v = T[(part*16+i)*33 + c]; s = fmaf(v, v, s); }
        red[part * 32 + c] = s;
    }
    {
        const int col = t >> 3;
        const int d0 = (t & 7) * 16;
        #pragma unroll
        for (int q = 0; q < 4; ++q) {
            f32x4 w;
            #pragma unroll
            for (int j = 0; j < 4; ++j) w[j] = T[(d0 + q*4 + j) * 33 + col];
            *(f32x4*)(ebT_f32 + (size_t)(k0 + col) * DDIM + d0 + q*4) = w;
        }
    }
    {
        const int l = t & 63;
        #pragma unroll
        for (int kk = 0; kk < 2; ++kk) {
            const int ks = (t >> 6) * 2 + kk;
            const int d0 = ks * 16 + (l >> 5) * 8;
            short8v hv;
            #pragma unroll
            for (int j = 0; j < 8; ++j) hv[j] = (short)bf16_rne(T[(d0 + j) * 33 + (l & 31)]);
            *(short8v*)(ebfrag + (size_t)ct * 8192 + ks * 1024 + l * 16) = hv;
        }
    }
    __syncthreads();
    if (t < 32) {
        float s = 0.f;
        #pragma unroll
        for (int p = 0; p < 8; ++p) s += red[p * 32 + t];
        enorm[k0 + t] = s;
    }
}

static __device__ __forceinline__ void gload_lds16(const char* src, char* lds_base) {
    __builtin_amdgcn_global_load_lds(
        (const __attribute__((address_space(1))) unsigned int*)src,
        (__attribute__((address_space(3))) unsigned int*)lds_base, 16, 0, 0);
}

// ---- k1: SLIM SCREEN. 32x32x16 MFMA, 2-pass split-bf16, packed top-3.
//      Output: keys[row][3] (packed dist|idx) + xsq partial into loss_acc.
//      No refine, no gather, no out-write. 2x16KB LDS dbuf, 16 phases.
__global__ __launch_bounds__(256, 3) void vq_screen(
    const float* __restrict__ x,
    const char* __restrict__ ebfrag,
    const float* __restrict__ enorm,
    float* __restrict__ keys,
    float* __restrict__ loss_acc)
{
    __shared__ char lds[32768];                  // 2 x 16KB double buffer
    const int tid = threadIdx.x, wid = tid >> 6, lane = tid & 63;
    const int cl = lane & 31, h = lane >> 5;
    const size_t wave_row = ((size_t)blockIdx.x * 4 + wid) * 32;

    // A fragments: row = wave_row + cl; lane covers d = ks*16 + h*8 + j
    short8v a_hi[8], a_lo[8];
    float xsq = 0.f;
    {
        const float* xrow = x + (wave_row + cl) * DDIM;
        #pragma unroll
        for (int ks = 0; ks < 8; ++ks) {
            const float* src = xrow + ks * 16 + h * 8;
            f32x4 v0 = *(const f32x4*)src;
            f32x4 v1 = *(const f32x4*)(src + 4);
            #pragma unroll
            for (int j = 0; j < 8; ++j) {
                float f = (j < 4) ? v0[j] : v1[j - 4];
                unsigned short hi = bf16_rne(f);
                float fh = bf16_to_f32(hi);
                a_hi[ks][j] = (short)hi;
                a_lo[ks][j] = (short)bf16_rne(f - fh);
                xsq = fmaf(f, f, xsq);
            }
        }
    }

    float tb[16], ts2[16], tt[16];
    #pragma unroll
    for (int r = 0; r < 16; ++r) { tb[r] = 3.4e38f; ts2[r] = 3.4e38f; tt[r] = 3.4e38f; }

    // stage phase 0: 16KB = 2 col-tiles; wave wid stages 4 x 1KB segments
    {
        const char* src = ebfrag + (size_t)wid * 4096 + lane * 16;
        char* dst = lds + wid * 4096;
        #pragma unroll
        for (int i = 0; i < 4; ++i)
            gload_lds16(src + i * 1024, dst + i * 1024);
    }
    __syncthreads();

    for (int p = 0; p < 16; ++p) {
        const char* cur = lds + (p & 1) * 16384;
        if (p < 15) {   // stage next 16KB into the other buffer
            const char* src = ebfrag + (size_t)(p + 1) * 16384 + (size_t)wid * 4096 + lane * 16;
            char* dst = lds + ((p + 1) & 1) * 16384 + wid * 4096;
            #pragma unroll
            for (int i = 0; i < 4; ++i)
                gload_lds16(src + i * 1024, dst + i * 1024);
        }
        // 2 col-tiles (32 cols each) per phase
        #pragma unroll
        for (int ctl = 0; ctl < 2; ++ctl) {
            const char* base = cur + ctl * 8192;
            short8v bh[8];
            #pragma unroll
            for (int ks = 0; ks < 8; ++ks)
                bh[ks] = *(const short8v*)(base + ks * 1024 + lane * 16);
            const int colv = (p * 2 + ctl) * 32 + cl;
            const float en = enorm[colv];
            f32x16 ah = (f32x16)(0.f), al = (f32x16)(0.f);
            #pragma unroll
            for (int ks = 0; ks < 8; ++ks) {
                ah = __builtin_amdgcn_mfma_f32_32x32x16_bf16(a_hi[ks], bh[ks], ah, 0, 0, 0);
                al = __builtin_amdgcn_mfma_f32_32x32x16_bf16(a_lo[ks], bh[ks], al, 0, 0, 0);
            }
            #pragma unroll
            for (int r = 0; r < 16; ++r) {
                float sim = ah[r] + al[r];
                float d = fmaf(-2.f, sim, en);            // ||x||^2 omitted
                unsigned db = __builtin_bit_cast(unsigned, d);
                float key = __builtin_bit_cast(float, (db & IDXMASK) | (unsigned)colv);
                tt[r]  = __builtin_amdgcn_fmed3f(key, ts2[r], tt[r]);
                ts2[r] = __builtin_amdgcn_fmed3f(key, tb[r],  ts2[r]);
                tb[r]  = fminf(key, tb[r]);
            }
        }
        __syncthreads();
    }

    // cross-lane top-3 merge over the 32 col-lanes
    #pragma unroll
    for (int r = 0; r < 16; ++r) {
        float b = tb[r], s = ts2[r], t3 = tt[r];
        #pragma unroll
        for (int off = 1; off < 32; off <<= 1) {
            float ob = __shfl_xor(b, off, 64);
            float os = __shfl_xor(s, off, 64);
            float ot = __shfl_xor(t3, off, 64);
            t3 = __builtin_amdgcn_fmed3f(ob, s, t3);
            s  = __builtin_amdgcn_fmed3f(ob, b, s);
            b  = fminf(b, ob);
            t3 = __builtin_amdgcn_fmed3f(os, s, t3);
            s  = fminf(s, os);
            t3 = fminf(t3, ot);
        }
        tb[r] = b; ts2[r] = s; tt[r] = t3;
    }

    // write keys: row = wave_row + 4h + (r&3) + 8*(r>>2); one writer per half
    if (cl == 0) {
        #pragma unroll
        for (int r = 0; r < 16; ++r) {
            const size_t row = wave_row + 4 * h + (r & 3) + 8 * (r >> 2);
            keys[row * 3 + 0] = tb[r];
            keys[row * 3 + 1] = ts2[r];
            keys[row * 3 + 2] = tt[r];
        }
    }

    // xsq partial (dist partial comes from k2 after refine)
    float part = xsq;
    #pragma unroll
    for (int off = 32; off > 0; off >>= 1) part += __shfl_down(part, off, 64);
    if (lane == 0) atomicAdd(loss_acc, part);
}

// ---- k2: per-row finalize. 16 lanes per row: gate + exact fp32 top-3 refine,
//      gather codeword to out, accumulate best-dist into loss.
__global__ __launch_bounds__(256) void vq_finalize_rows(
    const float* __restrict__ x,
    const float* __restrict__ ebT_f32,
    const float* __restrict__ enorm,
    const float* __restrict__ keys,
    float* __restrict__ out,
    float* __restrict__ loss_acc)
{
    __shared__ float bsum[16];
    const int tid = threadIdx.x;
    const int grp = tid >> 4, l16 = tid & 15;
    const size_t row = (size_t)blockIdx.x * 16 + grp;

    unsigned b1 = __builtin_bit_cast(unsigned, keys[row * 3 + 0]);
    unsigned b2 = __builtin_bit_cast(unsigned, keys[row * 3 + 1]);
    int chosen = (int)(b1 & 1023u);
    float dch = __builtin_bit_cast(float, b1 & IDXMASK);
    float d2a = __builtin_bit_cast(float, b2 & IDXMASK);

    if (d2a - dch < TAU) {           // uniform within the 16-lane group
        unsigned b3 = __builtin_bit_cast(unsigned, keys[row * 3 + 2]);
        int i1 = chosen, i2 = (int)(b2 & 1023u), i3 = (int)(b3 & 1023u);
        const f32x4* xp = (const f32x4*)(x + row * DDIM + l16 * 8);
        f32x4 x0 = xp[0], x1 = xp[1];
        const f32x4* e1 = (const f32x4*)(ebT_f32 + (size_t)i1 * DDIM + l16 * 8);
        const f32x4* e2 = (const f32x4*)(ebT_f32 + (size_t)i2 * DDIM + l16 * 8);
        const f32x4* e3 = (const f32x4*)(ebT_f32 + (size_t)i3 * DDIM + l16 * 8);
        f32x4 p10 = e1[0], p11 = e1[1];
        f32x4 p20 = e2[0], p21 = e2[1];
        f32x4 p30 = e3[0], p31 = e3[1];
        float q1 = 0.f, q2 = 0.f, q3 = 0.f;
        #pragma unroll
        for (int j = 0; j < 4; ++j) {
            q1 = fmaf(x0[j], p10[j], q1); q1 = fmaf(x1[j], p11[j], q1);
            q2 = fmaf(x0[j], p20[j], q2); q2 = fmaf(x1[j], p21[j], q2);
            q3 = fmaf(x0[j], p30[j], q3); q3 = fmaf(x1[j], p31[j], q3);
        }
        #pragma unroll
        for (int off = 1; off < 16; off <<= 1) {
            q1 += __shfl_xor(q1, off, 64);
            q2 += __shfl_xor(q2, off, 64);
            q3 += __shfl_xor(q3, off, 64);
        }
        float D1 = fmaf(-2.f, q1, enorm[i1]);
        float D2 = fmaf(-2.f, q2, enorm[i2]);
        float D3 = fmaf(-2.f, q3, enorm[i3]);
        float bd = D1; int bi = i1;
        if (D2 < bd || (D2 == bd && i2 < bi)) { bd = D2; bi = i2; }
        if (D3 < bd || (D3 == bd && i3 < bi)) { bd = D3; bi = i3; }
        chosen = bi; dch = bd;
    }

    // gather codeword -> out (coalesced: 16 lanes x 32B cover the 512B row)
    const f32x4* q = (const f32x4*)(ebT_f32 + (size_t)chosen * DDIM + l16 * 8);
    f32x4* dst = (f32x4*)(out + row * DDIM + l16 * 8);
    dst[0] = q[0];
    dst[1] = q[1];

    // loss partial: one dch per row -> block reduce -> one atomic
    if (l16 == 0) bsum[grp] = dch;
    __syncthreads();
    if (tid == 0) {
        float s = 0.f;
        #pragma unroll
        for (int i = 0; i < 16; ++i) s += bsum[i];
        atomicAdd(loss_acc, s);
    }
}

__global__ void vq_scalars(const float* __restrict__ loss_acc,
                           float* __restrict__ outl) {
    if (threadIdx.x == 0) {
        float l = loss_acc[0] * (1.0f / (float)TOTALF);
        outl[0] = l;           // codebook_loss
        outl[1] = 0.25f * l;   // commitment_loss = BETA * same value
    }
}

// ws layout: [0,512K) ebT_f32 | [512K,768K) ebfrag ([ct][ks][1KB], 256K)
//            [768K,772K) enorm | [772K,776K) loss_acc | [776K, 776K+1.5M) keys
extern "C" void kernel_launch(void* const* d_in, const int* in_sizes, int n_in,
                              void* d_out, int out_size, void* d_ws, size_t ws_size,
                              hipStream_t stream) {
    const float* x   = (const float*)d_in[0];
    const float* emb = (const float*)d_in[1];
    float* out = (float*)d_out;
    char* ws = (char*)d_ws;
    float* ebT_f32  = (float*)ws;
    char*  ebfrag   = ws + 512 * 1024;
    float* enormp   = (float*)(ws + 768 * 1024);
    float* loss_acc = (float*)(ws + 772 * 1024);
    float* keysp    = (float*)(ws + 776 * 1024);

    hipMemsetAsync(loss_acc, 0, sizeof(float), stream);
    vq_prep<<<32, 256, 0, stream>>>(emb, ebT_f32, ebfrag, enormp);
    vq_screen<<<NROWS / 128, 256, 0, stream>>>(x, ebfrag, enormp, keysp, loss_acc);
    vq_finalize_rows<<<NROWS / 16, 256, 0, stream>>>(x, ebT_f32, enormp, keysp, out, loss_acc);
    vq_scalars<<<1, 64, 0, stream>>>(loss_acc, out + (size_t)TOTALF);
}

// Round 13
// 139.932 us; speedup vs baseline: 2.2890x; 2.2890x over previous
//
#include <hip/hip_runtime.h>
#include <stdint.h>

#define NROWS (512*256)          // 131072
#define DDIM 128
#define KCB 1024
#define TOTALF (NROWS*DDIM)      // 16777216
#define TAU 0.35f                // refine gate vs 2nd-best gap (r5-proven)
#define IDXMASK 0xFFFFFC00u      // clear low 10 mantissa bits for packed argmin keys

typedef __attribute__((ext_vector_type(8))) short short8v;
typedef __attribute__((ext_vector_type(4))) float f32x4;
typedef __attribute__((ext_vector_type(16))) float f32x16;

static __device__ __forceinline__ unsigned short bf16_rne(float f) {
    unsigned u = __builtin_bit_cast(unsigned, f);
    u += 0x7FFFu + ((u >> 16) & 1u);
    return (unsigned short)(u >> 16);
}
static __device__ __forceinline__ float bf16_to_f32(unsigned short h) {
    unsigned u = ((unsigned)h) << 16;
    return __builtin_bit_cast(float, u);
}

// ---- prep (r11-proven): 32 blocks; block ct handles cols [ct*32, ct*32+32).
// Blob: [ct 0..31][ks 0..7][1024B]; seg ks lane l: col=ct*32+(l&31), d=ks*16+(l>>5)*8+j
__global__ __launch_bounds__(256) void vq_prep(
    const float* __restrict__ emb,
    float* __restrict__ ebT_f32,
    char* __restrict__ ebfrag,
    float* __restrict__ enorm)
{
    __shared__ float T[128 * 33];
    __shared__ float red[256];
    const int t = threadIdx.x;
    const int ct = blockIdx.x;
    const int k0 = ct * 32;
    {
        const int c = t & 31;
        const int dq = t >> 5;
        #pragma unroll
        for (int i = 0; i < 16; ++i) {
            int d = dq * 16 + i;
            T[d * 33 + c] = emb[(size_t)d * KCB + k0 + c];
        }
    }
    __syncthreads();
    {
        const int c = t & 31, part = t >> 5;
        float s = 0.f;
        #pragma unroll
        for (int i = 0; i < 16; ++i) { float v = T[(part*16+i)*33 + c]; s = fmaf(v, v, s); }
        red[part * 32 + c] = s;
    }
    {
        const int col = t >> 3;
        const int d0 = (t & 7) * 16;
        #pragma unroll
        for (int q = 0; q < 4; ++q) {
            f32x4 w;
            #pragma unroll
            for (int j = 0; j < 4; ++j) w[j] = T[(d0 + q*4 + j) * 33 + col];
            *(f32x4*)(ebT_f32 + (size_t)(k0 + col) * DDIM + d0 + q*4) = w;
        }
    }
    {
        const int l = t & 63;
        #pragma unroll
        for (int kk = 0; kk < 2; ++kk) {
            const int ks = (t >> 6) * 2 + kk;
            const int d0 = ks * 16 + (l >> 5) * 8;
            short8v hv;
            #pragma unroll
            for (int j = 0; j < 8; ++j) hv[j] = (short)bf16_rne(T[(d0 + j) * 33 + (l & 31)]);
            *(short8v*)(ebfrag + (size_t)ct * 8192 + ks * 1024 + l * 16) = hv;
        }
    }
    __syncthreads();
    if (t < 32) {
        float s = 0.f;
        #pragma unroll
        for (int p = 0; p < 8; ++p) s += red[p * 32 + t];
        enorm[k0 + t] = s;
    }
}

static __device__ __forceinline__ void gload_lds16(const char* src, char* lds_base) {
    __builtin_amdgcn_global_load_lds(
        (const __attribute__((address_space(1))) unsigned int*)src,
        (__attribute__((address_space(3))) unsigned int*)lds_base, 16, 0, 0);
}

// ---- main: r11 fused structure + T3/T4 counted-vmcnt pipeline (loads stay in
//      flight across barriers; no full drain in the main loop).
__global__ __launch_bounds__(256, 2) void vq_main(
    const float* __restrict__ x,
    const char* __restrict__ ebfrag,
    const float* __restrict__ ebT_f32,
    const float* __restrict__ enorm,
    float* __restrict__ out,
    float* __restrict__ loss_acc)
{
    __shared__ char lds[65536];                  // 2 x 32KB double buffer
    const int tid = threadIdx.x, wid = tid >> 6, lane = tid & 63;
    const int cl = lane & 31, h = lane >> 5;
    const size_t wave_row = ((size_t)blockIdx.x * 4 + wid) * 32;

    // A fragments: row = wave_row + cl; lane covers d = ks*16 + h*8 + j
    short8v a_hi[8], a_lo[8];
    float xsq = 0.f;
    {
        const float* xrow = x + (wave_row + cl) * DDIM;
        #pragma unroll
        for (int ks = 0; ks < 8; ++ks) {
            const float* src = xrow + ks * 16 + h * 8;
            f32x4 v0 = *(const f32x4*)src;
            f32x4 v1 = *(const f32x4*)(src + 4);
            #pragma unroll
            for (int j = 0; j < 8; ++j) {
                float f = (j < 4) ? v0[j] : v1[j - 4];
                unsigned short hi = bf16_rne(f);
                float fh = bf16_to_f32(hi);
                a_hi[ks][j] = (short)hi;
                a_lo[ks][j] = (short)bf16_rne(f - fh);
                xsq = fmaf(f, f, xsq);
            }
        }
    }

    float tb[16], ts2[16], tt[16];
    #pragma unroll
    for (int r = 0; r < 16; ++r) { tb[r] = 3.4e38f; ts2[r] = 3.4e38f; tt[r] = 3.4e38f; }

    // stage(q): wave wid's 8KB quarter of phase q into buf[q&1]
    #define STAGE(q) do {                                                         \
        const char* _s = ebfrag + (size_t)(q) * 32768 + (size_t)wid * 8192 + lane * 16; \
        char* _d = lds + ((q) & 1) * 32768 + wid * 8192;                          \
        _Pragma("unroll")                                                         \
        for (int _i = 0; _i < 8; ++_i)                                            \
            gload_lds16(_s + _i * 1024, _d + _i * 1024);                          \
    } while (0)

    // prologue: 2 phases in flight (16 outstanding loads/wave)
    STAGE(0);
    STAGE(1);

    for (int p = 0; p < 8; ++p) {
        // wait: phase-p loads (oldest 8) landed; phase-(p+1) loads may remain in flight
        if (p < 7) asm volatile("s_waitcnt vmcnt(8)" ::: "memory");
        else       asm volatile("s_waitcnt vmcnt(0)" ::: "memory");
        __builtin_amdgcn_sched_barrier(0);
        __builtin_amdgcn_s_barrier();            // all waves' phase-p data visible

        const char* cur = lds + (p & 1) * 32768;
        #pragma unroll
        for (int ctl = 0; ctl < 4; ++ctl) {
            const char* base = cur + ctl * 8192;
            short8v bh[8];
            #pragma unroll
            for (int ks = 0; ks < 8; ++ks)
                bh[ks] = *(const short8v*)(base + ks * 1024 + lane * 16);
            const int colv = (p * 4 + ctl) * 32 + cl;
            const float en = enorm[colv];
            f32x16 ah = (f32x16)(0.f), al = (f32x16)(0.f);
            #pragma unroll
            for (int ks = 0; ks < 8; ++ks) {
                ah = __builtin_amdgcn_mfma_f32_32x32x16_bf16(a_hi[ks], bh[ks], ah, 0, 0, 0);
                al = __builtin_amdgcn_mfma_f32_32x32x16_bf16(a_lo[ks], bh[ks], al, 0, 0, 0);
            }
            #pragma unroll
            for (int r = 0; r < 16; ++r) {
                float sim = ah[r] + al[r];
                float d = fmaf(-2.f, sim, en);            // ||x||^2 omitted
                unsigned db = __builtin_bit_cast(unsigned, d);
                float key = __builtin_bit_cast(float, (db & IDXMASK) | (unsigned)colv);
                tt[r]  = __builtin_amdgcn_fmed3f(key, ts2[r], tt[r]);   // new 3rd
                ts2[r] = __builtin_amdgcn_fmed3f(key, tb[r],  ts2[r]);  // new 2nd
                tb[r]  = fminf(key, tb[r]);                              // new 1st
            }
        }

        __builtin_amdgcn_s_barrier();            // all waves done reading buf[p&1]
        if (p < 6) STAGE(p + 2);                 // refill buf[p&1]; lands during p+1
    }
    #undef STAGE

    // cross-lane top-3 merge over the 32 col-lanes
    #pragma unroll
    for (int r = 0; r < 16; ++r) {
        float b = tb[r], s = ts2[r], t3 = tt[r];
        #pragma unroll
        for (int off = 1; off < 32; off <<= 1) {
            float ob = __shfl_xor(b, off, 64);
            float os = __shfl_xor(s, off, 64);
            float ot = __shfl_xor(t3, off, 64);
            t3 = __builtin_amdgcn_fmed3f(ob, s, t3);
            s  = __builtin_amdgcn_fmed3f(ob, b, s);
            b  = fminf(b, ob);
            t3 = __builtin_amdgcn_fmed3f(os, s, t3);
            s  = fminf(s, os);
            t3 = fminf(t3, ot);
        }
        tb[r] = b; ts2[r] = s; tt[r] = t3;
    }

    // refine + gather + loss; row = wave_row + 4h + (r&3) + 8*(r>>2)
    float lsum = 0.f;
    #pragma unroll
    for (int r = 0; r < 16; ++r) {
        unsigned b1 = __builtin_bit_cast(unsigned, tb[r]);
        unsigned b2 = __builtin_bit_cast(unsigned, ts2[r]);
        int chosen = (int)(b1 & 1023u);
        float dch = __builtin_bit_cast(float, b1 & IDXMASK);
        float d2a = __builtin_bit_cast(float, b2 & IDXMASK);
        const size_t row = wave_row + 4 * h + (r & 3) + 8 * (r >> 2);
        if (d2a - dch < TAU) {          // uniform within 32-lane half
            unsigned b3 = __builtin_bit_cast(unsigned, tt[r]);
            int i1 = chosen, i2 = (int)(b2 & 1023u), i3 = (int)(b3 & 1023u);
            f32x4 x0 = *(const f32x4*)(x + row * DDIM + cl * 4);
            f32x4 p1 = *(const f32x4*)(ebT_f32 + (size_t)i1 * DDIM + cl * 4);
            f32x4 p2 = *(const f32x4*)(ebT_f32 + (size_t)i2 * DDIM + cl * 4);
            f32x4 p3 = *(const f32x4*)(ebT_f32 + (size_t)i3 * DDIM + cl * 4);
            float q1 = 0.f, q2 = 0.f, q3 = 0.f;
            #pragma unroll
            for (int j = 0; j < 4; ++j) {
                q1 = fmaf(x0[j], p1[j], q1);
                q2 = fmaf(x0[j], p2[j], q2);
                q3 = fmaf(x0[j], p3[j], q3);
            }
            #pragma unroll
            for (int off = 1; off < 32; off <<= 1) {   // within-half butterfly
                q1 += __shfl_xor(q1, off, 64);
                q2 += __shfl_xor(q2, off, 64);
                q3 += __shfl_xor(q3, off, 64);
            }
            float D1 = fmaf(-2.f, q1, enorm[i1]);
            float D2 = fmaf(-2.f, q2, enorm[i2]);
            float D3 = fmaf(-2.f, q3, enorm[i3]);
            float bd = D1; int bi = i1;
            if (D2 < bd || (D2 == bd && i2 < bi)) { bd = D2; bi = i2; }
            if (D3 < bd || (D3 == bd && i3 < bi)) { bd = D3; bi = i3; }
            chosen = bi; dch = bd;
        }
        *(f32x4*)(out + row * DDIM + cl * 4) =
            *(const f32x4*)(ebT_f32 + (size_t)chosen * DDIM + cl * 4);
        if (cl == 0) lsum += dch;       // once per row (lanes 0 and 32, 16 rows each)
    }

    // loss: sum(||x||^2) + sum(best_dist) == sum((q-x)^2)
    float part = xsq + lsum;
    #pragma unroll
    for (int off = 32; off > 0; off >>= 1) part += __shfl_down(part, off, 64);
    if (lane == 0) atomicAdd(loss_acc, part);
}

__global__ void vq_finalize(const float* __restrict__ loss_acc,
                            float* __restrict__ outl) {
    if (threadIdx.x == 0) {
        float l = loss_acc[0] * (1.0f / (float)TOTALF);
        outl[0] = l;           // codebook_loss
        outl[1] = 0.25f * l;   // commitment_loss = BETA * same value
    }
}

// ws layout: [0,512K) ebT_f32 | [512K,768K) ebfrag ([ct][ks][1KB], 256K)
//            [768K,772K) enorm | [772K] loss_acc
extern "C" void kernel_launch(void* const* d_in, const int* in_sizes, int n_in,
                              void* d_out, int out_size, void* d_ws, size_t ws_size,
                              hipStream_t stream) {
    const float* x   = (const float*)d_in[0];
    const float* emb = (const float*)d_in[1];
    float* out = (float*)d_out;
    char* ws = (char*)d_ws;
    float* ebT_f32  = (float*)ws;
    char*  ebfrag   = ws + 512 * 1024;
    float* enormp   = (float*)(ws + 768 * 1024);
    float* loss_acc = (float*)(ws + 772 * 1024);

    hipMemsetAsync(loss_acc, 0, sizeof(float), stream);
    vq_prep<<<32, 256, 0, stream>>>(emb, ebT_f32, ebfrag, enormp);
    vq_main<<<NROWS / 128, 256, 0, stream>>>(x, ebfrag, ebT_f32, enormp, out, loss_acc);
    vq_finalize<<<1, 64, 0, stream>>>(loss_acc, out + (size_t)TOTALF);
}

// Round 14
// 119.828 us; speedup vs baseline: 2.6731x; 1.1678x over previous
//
#include <hip/hip_runtime.h>
#include <stdint.h>

#define NROWS (512*256)          // 131072
#define DDIM 128
#define KCB 1024
#define TOTALF (NROWS*DDIM)      // 16777216
#define TAU 0.35f                // refine gate vs 2nd-best gap (r5-proven)
#define IDXMASK 0xFFFFFC00u      // clear low 10 mantissa bits for packed argmin keys

typedef __attribute__((ext_vector_type(8))) short short8v;
typedef __attribute__((ext_vector_type(4))) float f32x4;
typedef __attribute__((ext_vector_type(16))) float f32x16;

static __device__ __forceinline__ unsigned short bf16_rne(float f) {
    unsigned u = __builtin_bit_cast(unsigned, f);
    u += 0x7FFFu + ((u >> 16) & 1u);
    return (unsigned short)(u >> 16);
}
static __device__ __forceinline__ float bf16_to_f32(unsigned short h) {
    unsigned u = ((unsigned)h) << 16;
    return __builtin_bit_cast(float, u);
}

// ---- prep (r11-proven): 32 blocks; block ct handles cols [ct*32, ct*32+32).
// Blob: [ct 0..31][ks 0..7][1024B]; seg ks lane l: col=ct*32+(l&31), d=ks*16+(l>>5)*8+j
__global__ __launch_bounds__(256) void vq_prep(
    const float* __restrict__ emb,
    float* __restrict__ ebT_f32,
    char* __restrict__ ebfrag,
    float* __restrict__ enorm)
{
    __shared__ float T[128 * 33];
    __shared__ float red[256];
    const int t = threadIdx.x;
    const int ct = blockIdx.x;
    const int k0 = ct * 32;
    {
        const int c = t & 31;
        const int dq = t >> 5;
        #pragma unroll
        for (int i = 0; i < 16; ++i) {
            int d = dq * 16 + i;
            T[d * 33 + c] = emb[(size_t)d * KCB + k0 + c];
        }
    }
    __syncthreads();
    {
        const int c = t & 31, part = t >> 5;
        float s = 0.f;
        #pragma unroll
        for (int i = 0; i < 16; ++i) { float v = T[(part*16+i)*33 + c]; s = fmaf(v, v, s); }
        red[part * 32 + c] = s;
    }
    {
        const int col = t >> 3;
        const int d0 = (t & 7) * 16;
        #pragma unroll
        for (int q = 0; q < 4; ++q) {
            f32x4 w;
            #pragma unroll
            for (int j = 0; j < 4; ++j) w[j] = T[(d0 + q*4 + j) * 33 + col];
            *(f32x4*)(ebT_f32 + (size_t)(k0 + col) * DDIM + d0 + q*4) = w;
        }
    }
    {
        const int l = t & 63;
        #pragma unroll
        for (int kk = 0; kk < 2; ++kk) {
            const int ks = (t >> 6) * 2 + kk;
            const int d0 = ks * 16 + (l >> 5) * 8;
            short8v hv;
            #pragma unroll
            for (int j = 0; j < 8; ++j) hv[j] = (short)bf16_rne(T[(d0 + j) * 33 + (l & 31)]);
            *(short8v*)(ebfrag + (size_t)ct * 8192 + ks * 1024 + l * 16) = hv;
        }
    }
    __syncthreads();
    if (t < 32) {
        float s = 0.f;
        #pragma unroll
        for (int p = 0; p < 8; ++p) s += red[p * 32 + t];
        enorm[k0 + t] = s;
    }
}

static __device__ __forceinline__ void gload_lds16(const char* src, char* lds_base) {
    __builtin_amdgcn_global_load_lds(
        (const __attribute__((address_space(1))) unsigned int*)src,
        (__attribute__((address_space(3))) unsigned int*)lds_base, 16, 0, 0);
}

// ---- main: r11 structure (plain dbuf staging), epilogue restructured for MLP:
//      resolve all chosen[] first, then batched independent gathers + stores.
__global__ __launch_bounds__(256, 2) void vq_main(
    const float* __restrict__ x,
    const char* __restrict__ ebfrag,
    const float* __restrict__ ebT_f32,
    const float* __restrict__ enorm,
    float* __restrict__ out,
    float* __restrict__ loss_acc)
{
    __shared__ char lds[65536];                  // 2 x 32KB double buffer
    const int tid = threadIdx.x, wid = tid >> 6, lane = tid & 63;
    const int cl = lane & 31, h = lane >> 5;
    const size_t wave_row = ((size_t)blockIdx.x * 4 + wid) * 32;

    // A fragments: row = wave_row + cl; lane covers d = ks*16 + h*8 + j
    short8v a_hi[8], a_lo[8];
    float xsq = 0.f;
    {
        const float* xrow = x + (wave_row + cl) * DDIM;
        #pragma unroll
        for (int ks = 0; ks < 8; ++ks) {
            const float* src = xrow + ks * 16 + h * 8;
            f32x4 v0 = *(const f32x4*)src;
            f32x4 v1 = *(const f32x4*)(src + 4);
            #pragma unroll
            for (int j = 0; j < 8; ++j) {
                float f = (j < 4) ? v0[j] : v1[j - 4];
                unsigned short hi = bf16_rne(f);
                float fh = bf16_to_f32(hi);
                a_hi[ks][j] = (short)hi;
                a_lo[ks][j] = (short)bf16_rne(f - fh);
                xsq = fmaf(f, f, xsq);
            }
        }
    }

    float tb[16], ts2[16], tt[16];
    #pragma unroll
    for (int r = 0; r < 16; ++r) { tb[r] = 3.4e38f; ts2[r] = 3.4e38f; tt[r] = 3.4e38f; }

    // stage phase 0: 32KB; wave wid stages 8 x 1KB segments
    {
        const char* src = ebfrag + (size_t)wid * 8192 + lane * 16;
        char* dst = lds + wid * 8192;
        #pragma unroll
        for (int i = 0; i < 8; ++i)
            gload_lds16(src + i * 1024, dst + i * 1024);
    }
    __syncthreads();

    for (int p = 0; p < 8; ++p) {
        const char* cur = lds + (p & 1) * 32768;
        if (p < 7) {
            const char* src = ebfrag + (size_t)(p + 1) * 32768 + (size_t)wid * 8192 + lane * 16;
            char* dst = lds + ((p + 1) & 1) * 32768 + wid * 8192;
            #pragma unroll
            for (int i = 0; i < 8; ++i)
                gload_lds16(src + i * 1024, dst + i * 1024);
        }
        #pragma unroll
        for (int ctl = 0; ctl < 4; ++ctl) {
            const char* base = cur + ctl * 8192;
            short8v bh[8];
            #pragma unroll
            for (int ks = 0; ks < 8; ++ks)
                bh[ks] = *(const short8v*)(base + ks * 1024 + lane * 16);
            const int colv = (p * 4 + ctl) * 32 + cl;
            const float en = enorm[colv];
            f32x16 ah = (f32x16)(0.f), al = (f32x16)(0.f);
            #pragma unroll
            for (int ks = 0; ks < 8; ++ks) {
                ah = __builtin_amdgcn_mfma_f32_32x32x16_bf16(a_hi[ks], bh[ks], ah, 0, 0, 0);
                al = __builtin_amdgcn_mfma_f32_32x32x16_bf16(a_lo[ks], bh[ks], al, 0, 0, 0);
            }
            #pragma unroll
            for (int r = 0; r < 16; ++r) {
                float sim = ah[r] + al[r];
                float d = fmaf(-2.f, sim, en);            // ||x||^2 omitted
                unsigned db = __builtin_bit_cast(unsigned, d);
                float key = __builtin_bit_cast(float, (db & IDXMASK) | (unsigned)colv);
                tt[r]  = __builtin_amdgcn_fmed3f(key, ts2[r], tt[r]);   // new 3rd
                ts2[r] = __builtin_amdgcn_fmed3f(key, tb[r],  ts2[r]);  // new 2nd
                tb[r]  = fminf(key, tb[r]);                              // new 1st
            }
        }
        __syncthreads();
    }

    // ---- phase A: cross-lane top-3 merge over the 32 col-lanes
    #pragma unroll
    for (int r = 0; r < 16; ++r) {
        float b = tb[r], s = ts2[r], t3 = tt[r];
        #pragma unroll
        for (int off = 1; off < 32; off <<= 1) {
            float ob = __shfl_xor(b, off, 64);
            float os = __shfl_xor(s, off, 64);
            float ot = __shfl_xor(t3, off, 64);
            t3 = __builtin_amdgcn_fmed3f(ob, s, t3);
            s  = __builtin_amdgcn_fmed3f(ob, b, s);
            b  = fminf(b, ob);
            t3 = __builtin_amdgcn_fmed3f(os, s, t3);
            s  = fminf(s, os);
            t3 = fminf(t3, ot);
        }
        tb[r] = b; ts2[r] = s; tt[r] = t3;
    }

    // ---- phase B: resolve chosen[16]/dch[16] (refine rare close calls)
    int   chosen[16];
    float dchv[16];
    #pragma unroll
    for (int r = 0; r < 16; ++r) {
        unsigned b1 = __builtin_bit_cast(unsigned, tb[r]);
        unsigned b2 = __builtin_bit_cast(unsigned, ts2[r]);
        int ch = (int)(b1 & 1023u);
        float dch = __builtin_bit_cast(float, b1 & IDXMASK);
        float d2a = __builtin_bit_cast(float, b2 & IDXMASK);
        const size_t row = wave_row + 4 * h + (r & 3) + 8 * (r >> 2);
        if (d2a - dch < TAU) {          // uniform within 32-lane half
            unsigned b3 = __builtin_bit_cast(unsigned, tt[r]);
            int i1 = ch, i2 = (int)(b2 & 1023u), i3 = (int)(b3 & 1023u);
            f32x4 x0 = *(const f32x4*)(x + row * DDIM + cl * 4);
            f32x4 p1 = *(const f32x4*)(ebT_f32 + (size_t)i1 * DDIM + cl * 4);
            f32x4 p2 = *(const f32x4*)(ebT_f32 + (size_t)i2 * DDIM + cl * 4);
            f32x4 p3 = *(const f32x4*)(ebT_f32 + (size_t)i3 * DDIM + cl * 4);
            float q1 = 0.f, q2 = 0.f, q3 = 0.f;
            #pragma unroll
            for (int j = 0; j < 4; ++j) {
                q1 = fmaf(x0[j], p1[j], q1);
                q2 = fmaf(x0[j], p2[j], q2);
                q3 = fmaf(x0[j], p3[j], q3);
            }
            #pragma unroll
            for (int off = 1; off < 32; off <<= 1) {   // within-half butterfly
                q1 += __shfl_xor(q1, off, 64);
                q2 += __shfl_xor(q2, off, 64);
                q3 += __shfl_xor(q3, off, 64);
            }
            float D1 = fmaf(-2.f, q1, enorm[i1]);
            float D2 = fmaf(-2.f, q2, enorm[i2]);
            float D3 = fmaf(-2.f, q3, enorm[i3]);
            float bd = D1; int bi = i1;
            if (D2 < bd || (D2 == bd && i2 < bi)) { bd = D2; bi = i2; }
            if (D3 < bd || (D3 == bd && i3 < bi)) { bd = D3; bi = i3; }
            ch = bi; dch = bd;
        }
        chosen[r] = ch;
        dchv[r] = dch;
    }

    // ---- phase C: batched gather + store (4 independent L2 loads per group)
    #pragma unroll
    for (int rq = 0; rq < 16; rq += 4) {
        f32x4 g0 = *(const f32x4*)(ebT_f32 + (size_t)chosen[rq+0] * DDIM + cl * 4);
        f32x4 g1 = *(const f32x4*)(ebT_f32 + (size_t)chosen[rq+1] * DDIM + cl * 4);
        f32x4 g2 = *(const f32x4*)(ebT_f32 + (size_t)chosen[rq+2] * DDIM + cl * 4);
        f32x4 g3 = *(const f32x4*)(ebT_f32 + (size_t)chosen[rq+3] * DDIM + cl * 4);
        const size_t rb = wave_row + 4 * h;
        *(f32x4*)(out + (rb + ((rq+0) & 3) + 8 * ((rq+0) >> 2)) * DDIM + cl * 4) = g0;
        *(f32x4*)(out + (rb + ((rq+1) & 3) + 8 * ((rq+1) >> 2)) * DDIM + cl * 4) = g1;
        *(f32x4*)(out + (rb + ((rq+2) & 3) + 8 * ((rq+2) >> 2)) * DDIM + cl * 4) = g2;
        *(f32x4*)(out + (rb + ((rq+3) & 3) + 8 * ((rq+3) >> 2)) * DDIM + cl * 4) = g3;
    }

    // loss: sum(||x||^2) + sum(best_dist) == sum((q-x)^2)
    float lsum = 0.f;
    if (cl == 0) {
        #pragma unroll
        for (int r = 0; r < 16; ++r) lsum += dchv[r];   // once per row
    }
    float part = xsq + lsum;
    #pragma unroll
    for (int off = 32; off > 0; off >>= 1) part += __shfl_down(part, off, 64);
    if (lane == 0) atomicAdd(loss_acc, part);
}

__global__ void vq_finalize(const float* __restrict__ loss_acc,
                            float* __restrict__ outl) {
    if (threadIdx.x == 0) {
        float l = loss_acc[0] * (1.0f / (float)TOTALF);
        outl[0] = l;           // codebook_loss
        outl[1] = 0.25f * l;   // commitment_loss = BETA * same value
    }
}

// ws layout: [0,512K) ebT_f32 | [512K,768K) ebfrag ([ct][ks][1KB], 256K)
//            [768K,772K) enorm | [772K] loss_acc
extern "C" void kernel_launch(void* const* d_in, const int* in_sizes, int n_in,
                              void* d_out, int out_size, void* d_ws, size_t ws_size,
                              hipStream_t stream) {
    const float* x   = (const float*)d_in[0];
    const float* emb = (const float*)d_in[1];
    float* out = (float*)d_out;
    char* ws = (char*)d_ws;
    float* ebT_f32  = (float*)ws;
    char*  ebfrag   = ws + 512 * 1024;
    float* enormp   = (float*)(ws + 768 * 1024);
    float* loss_acc = (float*)(ws + 772 * 1024);

    hipMemsetAsync(loss_acc, 0, sizeof(float), stream);
    vq_prep<<<32, 256, 0, stream>>>(emb, ebT_f32, ebfrag, enormp);
    vq_main<<<NROWS / 128, 256, 0, stream>>>(x, ebfrag, ebT_f32, enormp, out, loss_acc);
    vq_finalize<<<1, 64, 0, stream>>>(loss_acc, out + (size_t)TOTALF);
}

// Round 15
// 112.433 us; speedup vs baseline: 2.8489x; 1.0658x over previous
//
#include <hip/hip_runtime.h>
#include <stdint.h>

#define NROWS (512*256)          // 131072
#define DDIM 128
#define KCB 1024
#define TOTALF (NROWS*DDIM)      // 16777216
#define TAU 0.35f                // refine gate vs 2nd-best gap (r5-proven)
#define IDXMASK 0xFFFFFC00u      // clear low 10 mantissa bits for packed argmin keys

typedef __attribute__((ext_vector_type(8))) short short8v;
typedef __attribute__((ext_vector_type(4))) float f32x4;

static __device__ __forceinline__ unsigned short bf16_rne(float f) {
    unsigned u = __builtin_bit_cast(unsigned, f);
    u += 0x7FFFu + ((u >> 16) & 1u);
    return (unsigned short)(u >> 16);
}
static __device__ __forceinline__ float bf16_to_f32(unsigned short h) {
    unsigned u = ((unsigned)h) << 16;
    return __builtin_bit_cast(float, u);
}

// ---- prep: 64 blocks; block b handles cols [b*16, b*16+16).
// Blob layout: [ct 0..63][s 0..3][1024B], ct = global col-tile = blockIdx.
__global__ __launch_bounds__(256) void vq_prep(
    const float* __restrict__ emb,
    float* __restrict__ ebT_f32,
    char* __restrict__ ebfrag,
    float* __restrict__ enorm)
{
    __shared__ float T[128 * 17];
    __shared__ float red[256];
    const int t = threadIdx.x;
    const int k0 = blockIdx.x * 16;
    {
        const int c16 = t & 15;
        const int dq = t >> 4;
        #pragma unroll
        for (int i = 0; i < 8; ++i) {
            int d = dq * 8 + i;
            T[d * 17 + c16] = emb[(size_t)d * KCB + k0 + c16];
        }
    }
    __syncthreads();
    {
        const int c16 = t & 15, part = t >> 4;
        float s = 0.f;
        #pragma unroll
        for (int i = 0; i < 8; ++i) { float v = T[(part*8+i)*17 + c16]; s = fmaf(v, v, s); }
        red[part * 16 + c16] = s;
    }
    {
        const int col = t >> 4;
        const int d0 = (t & 15) * 8;
        f32x4 w0, w1;
        #pragma unroll
        for (int j = 0; j < 4; ++j) w0[j] = T[(d0 + j) * 17 + col];
        #pragma unroll
        for (int j = 0; j < 4; ++j) w1[j] = T[(d0 + 4 + j) * 17 + col];
        *(f32x4*)(ebT_f32 + (size_t)(k0 + col) * DDIM + d0) = w0;
        *(f32x4*)(ebT_f32 + (size_t)(k0 + col) * DDIM + d0 + 4) = w1;
    }
    {   // fragment-major bf16-hi blob, linear [ct][s][lane*16]
        const int s = t >> 6, l = t & 63;
        const int cc = l & 15, g = l >> 4;
        const int d0 = s * 32 + g * 8;
        short8v hv;
        #pragma unroll
        for (int j = 0; j < 8; ++j) hv[j] = (short)bf16_rne(T[(d0 + j) * 17 + cc]);
        *(short8v*)(ebfrag + (size_t)blockIdx.x * 4096 + s * 1024 + l * 16) = hv;
    }
    __syncthreads();
    if (t < 16) {
        float s = 0.f;
        #pragma unroll
        for (int p = 0; p < 16; ++p) s += red[p * 16 + t];
        enorm[k0 + t] = s;
    }
}

// async global->LDS, 16B per lane; lds_base wave-uniform, src per-lane
static __device__ __forceinline__ void gload_lds16(const char* src, char* lds_base) {
    __builtin_amdgcn_global_load_lds(
        (const __attribute__((address_space(1))) unsigned int*)src,
        (__attribute__((address_space(3))) unsigned int*)lds_base, 16, 0, 0);
}

// ---- main: B staged block-wide in LDS (2x32KB dbuf, 8 phases), r5 decision
//      logic unchanged (2-pass split-bf16, packed top-3, TAU=0.35 refine).
__global__ __launch_bounds__(256, 2) void vq_main(
    const float* __restrict__ x,
    const char* __restrict__ ebfrag,
    const float* __restrict__ ebT_f32,
    const float* __restrict__ enorm,
    float* __restrict__ out,
    float* __restrict__ loss_acc)
{
    __shared__ char lds[65536];                  // 2 x 32KB double buffer
    const int tid = threadIdx.x, wid = tid >> 6, lane = tid & 63;
    const int c = lane & 15, g = lane >> 4;
    const size_t wave_row = ((size_t)blockIdx.x * 4 + wid) * 64;

    // A fragments: 64 rows x 128 d, split hi/lo (layout r3/r5-proven)
    short8v a_hi[4][4], a_lo[4][4];
    float xsq = 0.f;
    #pragma unroll
    for (int m = 0; m < 4; ++m) {
      #pragma unroll
      for (int s = 0; s < 4; ++s) {
        const float* src = x + (wave_row + m * 16 + c) * DDIM + s * 32 + g * 8;
        f32x4 v0 = *(const f32x4*)src;
        f32x4 v1 = *(const f32x4*)(src + 4);
        #pragma unroll
        for (int j = 0; j < 8; ++j) {
            float f = (j < 4) ? v0[j] : v1[j - 4];
            unsigned short h = bf16_rne(f);
            float fh = bf16_to_f32(h);
            a_hi[m][s][j] = (short)h;
            a_lo[m][s][j] = (short)bf16_rne(f - fh);
            xsq = fmaf(f, f, xsq);
        }
      }
    }

    float tb[4][4], ts2[4][4], tt[4][4];
    #pragma unroll
    for (int m = 0; m < 4; ++m)
      #pragma unroll
      for (int r = 0; r < 4; ++r) { tb[m][r] = 3.4e38f; ts2[m][r] = 3.4e38f; tt[m][r] = 3.4e38f; }

    // stage phase 0: 32KB = 32 x 1KB segments; wave wid stages segs [wid*8, wid*8+8)
    {
        const char* src = ebfrag + (size_t)wid * 8192 + lane * 16;
        char* dst = lds + wid * 8192;
        #pragma unroll
        for (int i = 0; i < 8; ++i)
            gload_lds16(src + i * 1024, dst + i * 1024);
    }
    __syncthreads();

    for (int p = 0; p < 8; ++p) {
        const char* cur = lds + (p & 1) * 32768;
        if (p < 7) {   // stage next phase into the other buffer
            const char* src = ebfrag + (size_t)(p + 1) * 32768 + (size_t)wid * 8192 + lane * 16;
            char* dst = lds + ((p + 1) & 1) * 32768 + wid * 8192;
            #pragma unroll
            for (int i = 0; i < 8; ++i)
                gload_lds16(src + i * 1024, dst + i * 1024);
        }
        // compute 8 col-tiles from current buffer
        #pragma unroll 2
        for (int ctl = 0; ctl < 8; ++ctl) {
            short8v bh[4];
            #pragma unroll
            for (int s = 0; s < 4; ++s)
                bh[s] = *(const short8v*)(cur + ctl * 4096 + s * 1024 + lane * 16);
            const int colv = (p * 8 + ctl) * 16 + c;
            const float en = enorm[colv];
            f32x4 acc[4];
            #pragma unroll
            for (int m = 0; m < 4; ++m) acc[m] = (f32x4){0.f, 0.f, 0.f, 0.f};
            #pragma unroll
            for (int s = 0; s < 4; ++s) {
                #pragma unroll
                for (int m = 0; m < 4; ++m)
                    acc[m] = __builtin_amdgcn_mfma_f32_16x16x32_bf16(a_hi[m][s], bh[s], acc[m], 0, 0, 0);
                #pragma unroll
                for (int m = 0; m < 4; ++m)
                    acc[m] = __builtin_amdgcn_mfma_f32_16x16x32_bf16(a_lo[m][s], bh[s], acc[m], 0, 0, 0);
            }
            #pragma unroll
            for (int m = 0; m < 4; ++m)
              #pragma unroll
              for (int r = 0; r < 4; ++r) {
                float d = fmaf(-2.f, acc[m][r], en);      // ||x||^2 omitted
                unsigned db = __builtin_bit_cast(unsigned, d);
                float key = __builtin_bit_cast(float, (db & IDXMASK) | (unsigned)colv);
                tt[m][r]  = __builtin_amdgcn_fmed3f(key, ts2[m][r], tt[m][r]);  // new 3rd
                ts2[m][r] = __builtin_amdgcn_fmed3f(key, tb[m][r],  ts2[m][r]); // new 2nd
                tb[m][r]  = fminf(key, tb[m][r]);                                // new 1st
              }
        }
        __syncthreads();   // drains gload_lds (vmcnt0) + compute of this phase
    }

    // cross-lane top-3 merge over the 16 c-lanes (disjoint col sets)
    #pragma unroll
    for (int m = 0; m < 4; ++m)
      #pragma unroll
      for (int r = 0; r < 4; ++r) {
        float b = tb[m][r], s = ts2[m][r], t3 = tt[m][r];
        #pragma unroll
        for (int off = 1; off < 16; off <<= 1) {
            float ob = __shfl_xor(b, off, 64);
            float os = __shfl_xor(s, off, 64);
            float ot = __shfl_xor(t3, off, 64);
            t3 = __builtin_amdgcn_fmed3f(ob, s, t3);
            s  = __builtin_amdgcn_fmed3f(ob, b, s);
            b  = fminf(b, ob);
            t3 = __builtin_amdgcn_fmed3f(os, s, t3);
            s  = fminf(s, os);
            t3 = fminf(t3, ot);
        }
        tb[m][r] = b; ts2[m][r] = s; tt[m][r] = t3;
      }

    // refine: exact fp32 over top-3 where the 2nd-best gap is small
    float lsum = 0.f;
    #pragma unroll
    for (int m = 0; m < 4; ++m)
      #pragma unroll
      for (int r = 0; r < 4; ++r) {
        unsigned b1 = __builtin_bit_cast(unsigned, tb[m][r]);
        unsigned b2 = __builtin_bit_cast(unsigned, ts2[m][r]);
        int chosen = (int)(b1 & 1023u);
        float dch = __builtin_bit_cast(float, b1 & IDXMASK);
        float d2a = __builtin_bit_cast(float, b2 & IDXMASK);
        const size_t row = wave_row + m * 16 + g * 4 + r;
        if (d2a - dch < TAU) {      // uniform within 16-lane group
            unsigned b3 = __builtin_bit_cast(unsigned, tt[m][r]);
            int i1 = chosen, i2 = (int)(b2 & 1023u), i3 = (int)(b3 & 1023u);
            const f32x4* xp = (const f32x4*)(x + row * DDIM + c * 8);
            f32x4 x0 = xp[0], x1 = xp[1];
            const f32x4* e1 = (const f32x4*)(ebT_f32 + (size_t)i1 * DDIM + c * 8);
            const f32x4* e2 = (const f32x4*)(ebT_f32 + (size_t)i2 * DDIM + c * 8);
            const f32x4* e3 = (const f32x4*)(ebT_f32 + (size_t)i3 * DDIM + c * 8);
            f32x4 p10 = e1[0], p11 = e1[1];
            f32x4 p20 = e2[0], p21 = e2[1];
            f32x4 p30 = e3[0], p31 = e3[1];
            float q1 = 0.f, q2 = 0.f, q3 = 0.f;
            #pragma unroll
            for (int j = 0; j < 4; ++j) {
                q1 = fmaf(x0[j], p10[j], q1); q1 = fmaf(x1[j], p11[j], q1);
                q2 = fmaf(x0[j], p20[j], q2); q2 = fmaf(x1[j], p21[j], q2);
                q3 = fmaf(x0[j], p30[j], q3); q3 = fmaf(x1[j], p31[j], q3);
            }
            #pragma unroll
            for (int off = 1; off < 16; off <<= 1) {
                q1 += __shfl_xor(q1, off, 64);
                q2 += __shfl_xor(q2, off, 64);
                q3 += __shfl_xor(q3, off, 64);
            }
            float D1 = fmaf(-2.f, q1, enorm[i1]);
            float D2 = fmaf(-2.f, q2, enorm[i2]);
            float D3 = fmaf(-2.f, q3, enorm[i3]);
            float bd = D1; int bi = i1;
            if (D2 < bd || (D2 == bd && i2 < bi)) { bd = D2; bi = i2; }
            if (D3 < bd || (D3 == bd && i3 < bi)) { bd = D3; bi = i3; }
            chosen = bi; dch = bd;
        }
        const f32x4* qsrc = (const f32x4*)(ebT_f32 + (size_t)chosen * DDIM + c * 8);
        f32x4* dst = (f32x4*)(out + row * DDIM + c * 8);
        dst[0] = qsrc[0];
        dst[1] = qsrc[1];
        if (c == 0) lsum += dch;
      }

    // loss: sum(||x||^2) + sum(best_dist) == sum((q-x)^2)
    float part = xsq + lsum;
    #pragma unroll
    for (int off = 32; off > 0; off >>= 1) part += __shfl_down(part, off, 64);
    if (lane == 0) atomicAdd(loss_acc, part);
}

__global__ void vq_finalize(const float* __restrict__ loss_acc,
                            float* __restrict__ outl) {
    if (threadIdx.x == 0) {
        float l = loss_acc[0] * (1.0f / (float)TOTALF);
        outl[0] = l;           // codebook_loss
        outl[1] = 0.25f * l;   // commitment_loss = BETA * same value
    }
}

// ws layout: [0,512K) ebT_f32 | [512K,768K) ebfrag (linear [ct][s][1KB])
//            [768K,772K) enorm | [772K] loss_acc
extern "C" void kernel_launch(void* const* d_in, const int* in_sizes, int n_in,
                              void* d_out, int out_size, void* d_ws, size_t ws_size,
                              hipStream_t stream) {
    const float* x   = (const float*)d_in[0];
    const float* emb = (const float*)d_in[1];
    float* out = (float*)d_out;
    char* ws = (char*)d_ws;
    float* ebT_f32  = (float*)ws;
    char*  ebfrag   = ws + 512 * 1024;
    float* enormp   = (float*)(ws + 768 * 1024);
    float* loss_acc = (float*)(ws + 772 * 1024);

    hipMemsetAsync(loss_acc, 0, sizeof(float), stream);
    vq_prep<<<64, 256, 0, stream>>>(emb, ebT_f32, ebfrag, enormp);
    vq_main<<<NROWS / 256, 256, 0, stream>>>(x, ebfrag, ebT_f32, enormp, out, loss_acc);
    vq_finalize<<<1, 64, 0, stream>>>(loss_acc, out + (size_t)TOTALF);
}